// Round 2
// baseline (837.908 us; speedup 1.0000x reference)
//
#include <hip/hip_runtime.h>
#include <hip/hip_bf16.h>
#include <math.h>

// N=16384, D=4096, E=256, TOPK=6, scale=1.5
constexpr int D  = 4096;
constexpr int D4 = D / 4;
constexpr int E  = 256;
constexpr int TK = 6;

constexpr int BM = 64;     // rows per block
constexpr int BK = 32;     // k-slice per LDS tile
constexpr int AP = BM + 4; // As pitch (floats)
constexpr int BP = E + 4;  // Bs pitch (floats)
constexpr int NT = 512;    // threads per block

// Block: 64 rows x all 256 experts. 512 threads, micro-tile 4 rows x 8 experts.
// tx = t&31 -> experts [8tx, 8tx+8); ty = t>>5 -> rows [4ty, 4ty+4).
// fp32 fma within a BK=32 tile, fp64 cross-tile accumulation (score err ~1.4e-7,
// needed so top-6 ranking matches the high-precision numpy reference).
__global__ __launch_bounds__(NT, 2)
void gate_kernel(const float* __restrict__ xg,
                 const float* __restrict__ wg,
                 const float* __restrict__ bg,
                 float* __restrict__ outw,   // [N,6] weights
                 float* __restrict__ outi)   // [N,6] indices stored as float
{
    __shared__ float As[BK * AP];   //  8704 B
    __shared__ float Bs[BK * BP];   // 33280 B
    __shared__ float bias_s[E];     //  1024 B

    const int t    = threadIdx.x;
    const int tx   = t & 31;
    const int ty   = t >> 5;
    const int row0 = blockIdx.x * BM;

    if (t < E) bias_s[t] = bg[t];

    const float4* x4 = reinterpret_cast<const float4*>(xg);
    const float4* w4 = reinterpret_cast<const float4*>(wg);

    double accd[4][8];
    float  t32[4][8];
#pragma unroll
    for (int i = 0; i < 4; ++i)
#pragma unroll
        for (int j = 0; j < 8; ++j) { accd[i][j] = 0.0; t32[i][j] = 0.f; }

    // Staging: A tile 64 rows x 8 float4 = 512 f4 -> 1/thread.
    //          B tile 256 rows x 8 float4 = 2048 f4 -> 4/thread.
    const int srow = t >> 3;   // 0..63
    const int scol = t & 7;    // f4 column within 32-wide k slice

    float4 aP, bP[4];
    auto load_tile = [&](int k0f4) {
        aP = x4[(size_t)(row0 + srow) * D4 + k0f4 + scol];
#pragma unroll
        for (int q = 0; q < 4; ++q)
            bP[q] = w4[(size_t)(srow + 64 * q) * D4 + k0f4 + scol];
    };
    auto store_tile = [&]() {
        const int kb = scol * 4;
        As[(kb + 0) * AP + srow] = aP.x;
        As[(kb + 1) * AP + srow] = aP.y;
        As[(kb + 2) * AP + srow] = aP.z;
        As[(kb + 3) * AP + srow] = aP.w;
#pragma unroll
        for (int q = 0; q < 4; ++q) {
            const int e = srow + 64 * q;
            Bs[(kb + 0) * BP + e] = bP[q].x;
            Bs[(kb + 1) * BP + e] = bP[q].y;
            Bs[(kb + 2) * BP + e] = bP[q].z;
            Bs[(kb + 3) * BP + e] = bP[q].w;
        }
    };

    load_tile(0);
    store_tile();

    const int NIT = D / BK;  // 128
    for (int it = 0; it < NIT; ++it) {
        __syncthreads();                       // tile `it` visible
        if (it + 1 < NIT) load_tile((it + 1) * (BK / 4));

#pragma unroll 8
        for (int kk = 0; kk < BK; ++kk) {
            const float4 a  = *reinterpret_cast<const float4*>(&As[kk * AP + ty * 4]);
            const float4 b0 = *reinterpret_cast<const float4*>(&Bs[kk * BP + tx * 8 + 0]);
            const float4 b1 = *reinterpret_cast<const float4*>(&Bs[kk * BP + tx * 8 + 4]);
            const float av[4] = { a.x, a.y, a.z, a.w };
            const float bv[8] = { b0.x,b0.y,b0.z,b0.w, b1.x,b1.y,b1.z,b1.w };
#pragma unroll
            for (int i = 0; i < 4; ++i)
#pragma unroll
                for (int j = 0; j < 8; ++j)
                    t32[i][j] = fmaf(av[i], bv[j], t32[i][j]);
        }

        // fold tile partial into fp64 accumulator (exact cross-tile sum)
#pragma unroll
        for (int i = 0; i < 4; ++i)
#pragma unroll
            for (int j = 0; j < 8; ++j) {
                accd[i][j] += (double)t32[i][j];
                t32[i][j] = 0.f;
            }

        __syncthreads();                       // done reading tile `it`
        if (it + 1 < NIT) store_tile();
    }

    // Epilogue in fp64: biased = sqrt(softplus(s)) + bias. Store biased in accd.
#pragma unroll
    for (int i = 0; i < 4; ++i)
#pragma unroll
        for (int j = 0; j < 8; ++j) {
            const double s  = accd[i][j];
            const double sp = fmax(s, 0.0) + log1p(exp(-fabs(s)));
            accd[i][j] = sqrt(sp) + (double)bias_s[tx * 8 + j];
        }

    // Top-6 per row across the 32 lanes sharing ty (lanes contiguous in wave;
    // xor offsets < 32 stay inside the 32-lane half).
#pragma unroll
    for (int i = 0; i < 4; ++i) {
        double v[8];
#pragma unroll
        for (int j = 0; j < 8; ++j) v[j] = accd[i][j];

        double wv[TK];
        int    wi_[TK];
        double wsum = 0.0;

#pragma unroll
        for (int s = 0; s < TK; ++s) {
            // local argmax over 8 (strict > keeps lowest index on tie)
            double bv = v[0]; int bj = 0;
#pragma unroll
            for (int j = 1; j < 8; ++j)
                if (v[j] > bv) { bv = v[j]; bj = j; }
            int bi = tx * 8 + bj;
            // butterfly over 32 lanes; tie -> lower expert index (jax top_k)
#pragma unroll
            for (int off = 1; off < 32; off <<= 1) {
                const double ov = __shfl_xor(bv, off, 64);
                const int    oi = __shfl_xor(bi, off, 64);
                if (ov > bv || (ov == bv && oi < bi)) { bv = ov; bi = oi; }
            }
            const double orig = bv - (double)bias_s[bi];  // exact to ~1 ulp64
            wv[s] = orig; wi_[s] = bi; wsum += orig;
            // deactivate winner in its owner lane (static indices only)
            if ((bi >> 3) == tx) {
                const int jj = bi & 7;
#pragma unroll
                for (int j = 0; j < 8; ++j)
                    if (j == jj) v[j] = -1.0e300;
            }
        }

        if (tx == 0) {
            const int r = row0 + ty * 4 + i;
            const double sc = 1.5 / wsum;
#pragma unroll
            for (int s = 0; s < TK; ++s) {
                outw[(size_t)r * TK + s] = (float)(wv[s] * sc);
                outi[(size_t)r * TK + s] = (float)wi_[s];
            }
        }
    }
}

extern "C" void kernel_launch(void* const* d_in, const int* in_sizes, int n_in,
                              void* d_out, int out_size, void* d_ws, size_t ws_size,
                              hipStream_t stream) {
    const float* x = (const float*)d_in[0];
    const float* w = (const float*)d_in[1];
    const float* b = (const float*)d_in[2];
    float* out = (float*)d_out;

    const int N = in_sizes[0] / D;          // 16384
    float* outw = out;                      // [N,6] weights
    float* outi = out + (size_t)N * TK;     // [N,6] indices (as float)

    hipLaunchKernelGGL(gate_kernel, dim3(N / BM), dim3(NT), 0, stream,
                       x, w, b, outw, outi);
}

// Round 3
// 642.879 us; speedup vs baseline: 1.3034x; 1.3034x over previous
//
#include <hip/hip_runtime.h>
#include <math.h>

// N=16384, D=4096, E=256, TOPK=6, scale=1.5
constexpr int D     = 4096;
constexpr int D4    = 1024;     // float4 per row
constexpr int E     = 256;
constexpr int TK    = 6;
constexpr int BM    = 64;       // rows per block
constexpr int BK    = 32;       // K per LDS tile
constexpr int BKP   = 40;       // LDS pitch in shorts (16B-aligned rows)
constexpr int NT    = 512;      // threads (8 waves)
constexpr int NTILE = D / BK;   // 128
constexpr float TAU = 3e-5f;    // ambiguity threshold (~15 sigma of approx err)

typedef __attribute__((ext_vector_type(8)))  short short8;
typedef __attribute__((ext_vector_type(16))) float float16;
typedef unsigned short ushort_t;

__device__ __forceinline__ ushort_t f2bf(float f) {  // RTNE fp32->bf16
  unsigned u = __float_as_uint(f);
  return (ushort_t)((u + 0x7fffu + ((u >> 16) & 1u)) >> 16);
}
__device__ __forceinline__ float bf2f(ushort_t h) {
  return __uint_as_float(((unsigned)h) << 16);
}

struct SMem {
  union {
    struct {                       // phase-1 staging (51.2 KB)
      ushort_t As_hi[BM * BKP];
      ushort_t As_lo[BM * BKP];
      ushort_t Bs_hi[E * BKP];
      ushort_t Bs_lo[E * BKP];
    } st;
    struct {                       // merge buffer (16.9 KB), used after staging dead
      float val[BM * 33];          // [row][slot<32], pitch 33 breaks bank alignment
      int   id [BM * 33];
    } mg;
  } u;
  float  bias[E];
  int    nflag;
  int    flagrow[BM];
  int    flagid[BM][8];
  double exact[8];
};

__global__ __launch_bounds__(NT, 2)
void gate_kernel(const float* __restrict__ xg, const float* __restrict__ wg,
                 const float* __restrict__ bg, float* __restrict__ outw,
                 float* __restrict__ outi)
{
  __shared__ SMem sm;
  const int t    = threadIdx.x;
  const int row0 = blockIdx.x * BM;
  const int wv   = t >> 6;       // wave 0..7
  const int lane = t & 63;
  const int rb   = wv & 1;       // row band (32 rows)
  const int eg   = wv >> 1;      // expert group (64 experts)

  if (t < E) sm.bias[t] = bg[t];
  if (t == 0) sm.nflag = 0;

  const float4* x4 = (const float4*)xg;
  const float4* w4 = (const float4*)wg;

  float16 acc0, acc1;
#pragma unroll
  for (int i = 0; i < 16; ++i) { acc0[i] = 0.f; acc1[i] = 0.f; }

  // Staging: A 64x8 f4 -> 1 f4/thread; B 256x8 f4 -> 4 f4/thread
  const int a_row = t >> 3, a_c = t & 7;
  const int b_e   = t >> 1, b_h = t & 1;
  float4 aP, bP[4];

  auto load_regs = [&](int kt) {
    aP = x4[(size_t)(row0 + a_row) * D4 + kt * 8 + a_c];
#pragma unroll
    for (int q = 0; q < 4; ++q)
      bP[q] = w4[(size_t)b_e * D4 + kt * 8 + b_h * 4 + q];
  };
  auto store_tile = [&]() {
    ushort_t hi[4], lo[4];
    float av[4] = {aP.x, aP.y, aP.z, aP.w};
#pragma unroll
    for (int i = 0; i < 4; ++i) {
      hi[i] = f2bf(av[i]);
      lo[i] = f2bf(av[i] - bf2f(hi[i]));
    }
    *(uint2*)&sm.u.st.As_hi[a_row * BKP + a_c * 4] = *(uint2*)hi;
    *(uint2*)&sm.u.st.As_lo[a_row * BKP + a_c * 4] = *(uint2*)lo;
    ushort_t bhi[16], blo[16];
#pragma unroll
    for (int q = 0; q < 4; ++q) {
      float wv4[4] = {bP[q].x, bP[q].y, bP[q].z, bP[q].w};
#pragma unroll
      for (int i = 0; i < 4; ++i) {
        bhi[q*4+i] = f2bf(wv4[i]);
        blo[q*4+i] = f2bf(wv4[i] - bf2f(bhi[q*4+i]));
      }
    }
    *(uint4*)&sm.u.st.Bs_hi[b_e * BKP + b_h * 16 + 0] = *(uint4*)&bhi[0];
    *(uint4*)&sm.u.st.Bs_hi[b_e * BKP + b_h * 16 + 8] = *(uint4*)&bhi[8];
    *(uint4*)&sm.u.st.Bs_lo[b_e * BKP + b_h * 16 + 0] = *(uint4*)&blo[0];
    *(uint4*)&sm.u.st.Bs_lo[b_e * BKP + b_h * 16 + 8] = *(uint4*)&blo[8];
  };

  // MFMA fragment addressing (32x32x16 bf16): A m=lane&31, k=(lane>>5)*8+j;
  // B n=lane&31, same k split; C col=lane&31, row=(reg&3)+8*(reg>>2)+4*(lane>>5)
  const int m  = lane & 31;
  const int hf = lane >> 5;
  const int arow = (rb * 32 + m) * BKP + hf * 8;
  const int ebase0 = (eg * 64 +      m) * BKP + hf * 8;
  const int ebase1 = (eg * 64 + 32 + m) * BKP + hf * 8;

  load_regs(0);
  for (int it = 0; it < NTILE; ++it) {
    store_tile();
    __syncthreads();
    if (it + 1 < NTILE) load_regs(it + 1);
#pragma unroll
    for (int ks = 0; ks < 2; ++ks) {
      const int ko = ks * 16;
      short8 ahi = *(const short8*)&sm.u.st.As_hi[arow + ko];
      short8 alo = *(const short8*)&sm.u.st.As_lo[arow + ko];
      short8 b0h = *(const short8*)&sm.u.st.Bs_hi[ebase0 + ko];
      short8 b0l = *(const short8*)&sm.u.st.Bs_lo[ebase0 + ko];
      short8 b1h = *(const short8*)&sm.u.st.Bs_hi[ebase1 + ko];
      short8 b1l = *(const short8*)&sm.u.st.Bs_lo[ebase1 + ko];
      acc0 = __builtin_amdgcn_mfma_f32_32x32x16_bf16(ahi, b0h, acc0, 0, 0, 0);
      acc0 = __builtin_amdgcn_mfma_f32_32x32x16_bf16(ahi, b0l, acc0, 0, 0, 0);
      acc0 = __builtin_amdgcn_mfma_f32_32x32x16_bf16(alo, b0h, acc0, 0, 0, 0);
      acc1 = __builtin_amdgcn_mfma_f32_32x32x16_bf16(ahi, b1h, acc1, 0, 0, 0);
      acc1 = __builtin_amdgcn_mfma_f32_32x32x16_bf16(ahi, b1l, acc1, 0, 0, 0);
      acc1 = __builtin_amdgcn_mfma_f32_32x32x16_bf16(alo, b1h, acc1, 0, 0, 0);
    }
    __syncthreads();
  }

  // ---- per-wave top-8 over this wave's 64 experts, per row ----
  const int e0id = eg * 64 + m;
  const int e1id = eg * 64 + 32 + m;
  const float bia0 = sm.bias[e0id];
  const float bia1 = sm.bias[e1id];

#pragma unroll
  for (int reg = 0; reg < 16; ++reg) {
    const int row_local = rb * 32 + (reg & 3) + 8 * (reg >> 2) + 4 * hf;
    float s0 = acc0[reg], s1 = acc1[reg];
    float v0 = sqrtf(fmaxf(s0, 0.f) + log1pf(expf(-fabsf(s0)))) + bia0;
    float v1 = sqrtf(fmaxf(s1, 0.f) + log1pf(expf(-fabsf(s1)))) + bia1;
    float tv[8]; int ti[8];
#pragma unroll
    for (int s = 0; s < 8; ++s) {
      float bv; int bi;
      if (v0 >= v1) { bv = v0; bi = e0id; } else { bv = v1; bi = e1id; }
#pragma unroll
      for (int off = 1; off < 32; off <<= 1) {
        float ov = __shfl_xor(bv, off, 64);
        int   oi = __shfl_xor(bi, off, 64);
        if (ov > bv || (ov == bv && oi < bi)) { bv = ov; bi = oi; }
      }
      tv[s] = bv; ti[s] = bi;
      if (bi == e0id) v0 = -INFINITY;
      else if (bi == e1id) v1 = -INFINITY;
    }
    if (m == 0) {
#pragma unroll
      for (int s = 0; s < 8; ++s) {
        sm.u.mg.val[row_local * 33 + eg * 8 + s] = tv[s];
        sm.u.mg.id [row_local * 33 + eg * 8 + s] = ti[s];
      }
    }
  }
  __syncthreads();

  // ---- merge 4x8 -> global top-8 per row; flag ambiguous rows ----
  {
    const int r = t >> 3, g = t & 7;
    float mv[4]; int mi[4];
#pragma unroll
    for (int q = 0; q < 4; ++q) {
      mv[q] = sm.u.mg.val[r * 33 + q * 8 + g];
      mi[q] = sm.u.mg.id [r * 33 + q * 8 + g];
    }
    float tv[8]; int ti[8];
#pragma unroll
    for (int s = 0; s < 8; ++s) {
      float bv = mv[0]; int bi = mi[0];
#pragma unroll
      for (int q = 1; q < 4; ++q)
        if (mv[q] > bv || (mv[q] == bv && mi[q] < bi)) { bv = mv[q]; bi = mi[q]; }
#pragma unroll
      for (int off = 1; off < 8; off <<= 1) {
        float ov = __shfl_xor(bv, off, 64);
        int   oi = __shfl_xor(bi, off, 64);
        if (ov > bv || (ov == bv && oi < bi)) { bv = ov; bi = oi; }
      }
      tv[s] = bv; ti[s] = bi;
#pragma unroll
      for (int q = 0; q < 4; ++q)
        if (mi[q] == bi) mv[q] = -INFINITY;
    }
    if (g == 0) {
      bool flag = false;
#pragma unroll
      for (int i = 0; i < 7; ++i) flag |= (tv[i] - tv[i+1] < TAU);
      const int grow = row0 + r;
      if (!flag) {
        float og[6], ssum = 0.f;
#pragma unroll
        for (int i = 0; i < 6; ++i) { og[i] = tv[i] - sm.bias[ti[i]]; ssum += og[i]; }
        const float sc = 1.5f / ssum;
#pragma unroll
        for (int i = 0; i < 6; ++i) {
          outw[(size_t)grow * TK + i] = og[i] * sc;
          outi[(size_t)grow * TK + i] = (float)ti[i];
        }
      } else {
        int slot = atomicAdd(&sm.nflag, 1);
        sm.flagrow[slot] = grow;
#pragma unroll
        for (int i = 0; i < 8; ++i) sm.flagid[slot][i] = ti[i];
      }
    }
  }
  __syncthreads();

  // ---- exact fp64 rescue for flagged rows (expected ~0.3/block) ----
  const int nf = sm.nflag;
  for (int f = 0; f < nf; ++f) {
    const int grow = sm.flagrow[f];
    const int e    = sm.flagid[f][wv];
    double accd = 0.0;
    const float4* xr = x4 + (size_t)grow * D4 + lane * 16;
    const float4* wr = w4 + (size_t)e    * D4 + lane * 16;
#pragma unroll
    for (int i = 0; i < 16; ++i) {
      float4 xv = xr[i], wl = wr[i];
      accd = fma((double)xv.x, (double)wl.x, accd);
      accd = fma((double)xv.y, (double)wl.y, accd);
      accd = fma((double)xv.z, (double)wl.z, accd);
      accd = fma((double)xv.w, (double)wl.w, accd);
    }
#pragma unroll
    for (int off = 1; off < 64; off <<= 1)
      accd += __shfl_xor(accd, off, 64);
    if (lane == 0) {
      double sp = fmax(accd, 0.0) + log1p(exp(-fabs(accd)));
      sm.exact[wv] = sqrt(sp);   // orig (unbiased) score
    }
    __syncthreads();
    if (t == 0) {
      double ov[8]; int oid[8], ordr[8];
      for (int i = 0; i < 8; ++i) { ov[i] = sm.exact[i]; oid[i] = sm.flagid[f][i]; ordr[i] = i; }
      for (int i = 0; i < 6; ++i) {
        int b = i;
        for (int j = i + 1; j < 8; ++j) {
          double bj = ov[ordr[j]] + (double)sm.bias[oid[ordr[j]]];
          double bb = ov[ordr[b]] + (double)sm.bias[oid[ordr[b]]];
          if (bj > bb || (bj == bb && oid[ordr[j]] < oid[ordr[b]])) b = j;
        }
        int tmp = ordr[i]; ordr[i] = ordr[b]; ordr[b] = tmp;
      }
      double ssum = 0.0;
      for (int i = 0; i < 6; ++i) ssum += ov[ordr[i]];
      double sc = 1.5 / ssum;
      for (int i = 0; i < 6; ++i) {
        outw[(size_t)grow * TK + i] = (float)(ov[ordr[i]] * sc);
        outi[(size_t)grow * TK + i] = (float)oid[ordr[i]];
      }
    }
    __syncthreads();
  }
}

extern "C" void kernel_launch(void* const* d_in, const int* in_sizes, int n_in,
                              void* d_out, int out_size, void* d_ws, size_t ws_size,
                              hipStream_t stream) {
  const float* x = (const float*)d_in[0];
  const float* w = (const float*)d_in[1];
  const float* b = (const float*)d_in[2];
  float* out  = (float*)d_out;
  const int N = in_sizes[0] / D;          // 16384
  float* outw = out;                      // [N,6] weights
  float* outi = out + (size_t)N * TK;     // [N,6] indices (as float)
  hipLaunchKernelGGL(gate_kernel, dim3(N / BM), dim3(NT), 0, stream,
                     x, w, b, outw, outi);
}

// Round 4
// 567.582 us; speedup vs baseline: 1.4763x; 1.1327x over previous
//
#include <hip/hip_runtime.h>
#include <math.h>

// N=16384, D=4096, E=256, TOPK=6, scale=1.5
constexpr int D     = 4096;
constexpr int D4    = 1024;     // float4 per row
constexpr int E     = 256;
constexpr int TK    = 6;
constexpr int BM    = 64;       // rows per block
constexpr int NT    = 512;      // 8 waves
constexpr int NTILE = 128;      // D / 32
constexpr float TAU = 3e-5f;    // ambiguity threshold (~7-15 sigma of approx err)

typedef __attribute__((ext_vector_type(8)))  short short8;
typedef __attribute__((ext_vector_type(16))) float float16;
typedef unsigned short ushort_t;

#define GAS __attribute__((address_space(1)))
#define LAS __attribute__((address_space(3)))

__device__ __forceinline__ ushort_t f2bf(float f) {  // RTNE fp32->bf16
  unsigned u = __float_as_uint(f);
  return (ushort_t)((u + 0x7fffu + ((u >> 16) & 1u)) >> 16);
}
__device__ __forceinline__ float bf2f(ushort_t h) {
  return __uint_as_float(((unsigned)h) << 16);
}
__device__ __forceinline__ int swz4(int r) { return (r & 3) ^ ((r >> 2) & 3); }

// async 16B global -> LDS (lds dest = uniform base + lane*16)
__device__ __forceinline__ void gload_lds16(const ushort_t* g, ushort_t* l) {
  __builtin_amdgcn_global_load_lds((const GAS unsigned int*)g,
                                   (LAS unsigned int*)l, 16, 0, 0);
}

struct __align__(16) SMem {
  union {
    struct {                     // double-buffered staging: 80 KB
      ushort_t Bh[2][E * 32];
      ushort_t Bl[2][E * 32];
      ushort_t Ah[2][BM * 32];
      ushort_t Al[2][BM * 32];
    } st;
    struct {                     // merge buffer (union: staging dead by then)
      float val[BM * 33];
      int   id [BM * 33];
    } mg;
  } u;
  float  bias[E];
  int    nflag;
  int    flagrow[BM];
  int    flagid[BM][8];
  double exact[8];
};

// ---------- prepass: W fp32 -> bf16 hi/lo in workspace ----------
__global__ __launch_bounds__(256)
void conv_w(const float* __restrict__ wg, ushort_t* __restrict__ whi,
            ushort_t* __restrict__ wlo)
{
  size_t i = (size_t)blockIdx.x * 256 + threadIdx.x;   // over E*D/4
  float4 v = ((const float4*)wg)[i];
  float a[4] = {v.x, v.y, v.z, v.w};
  ushort_t h[4], l[4];
#pragma unroll
  for (int j = 0; j < 4; ++j) {
    h[j] = f2bf(a[j]);
    l[j] = f2bf(a[j] - bf2f(h[j]));
  }
  *(uint2*)&whi[i * 4] = *(uint2*)h;
  *(uint2*)&wlo[i * 4] = *(uint2*)l;
}

// ---------- main fused kernel ----------
__global__ __launch_bounds__(NT, 2)
void gate_kernel(const float* __restrict__ xg, const float* __restrict__ wg,
                 const float* __restrict__ bg,
                 const ushort_t* __restrict__ whi, const ushort_t* __restrict__ wlo,
                 float* __restrict__ outw, float* __restrict__ outi)
{
  __shared__ SMem sm;
  const int t    = threadIdx.x;
  const int row0 = blockIdx.x * BM;
  const int wv   = t >> 6;       // wave 0..7
  const int lane = t & 63;
  const int rb   = wv & 1;       // row band (32 rows)
  const int eg   = wv >> 1;      // expert group (64 experts)

  if (t < E) sm.bias[t] = bg[t];
  if (t == 0) sm.nflag = 0;

  const float4* x4 = (const float4*)xg;
  const float4* w4 = (const float4*)wg;

  float16 acc0, acc1;
#pragma unroll
  for (int i = 0; i < 16; ++i) { acc0[i] = 0.f; acc1[i] = 0.f; }

  // A staging roles: 1 float4/thread
  const int a_row = t >> 3;      // 0..63
  const int a_c   = t & 7;       // f4 column within 32-wide k slice
  float4 xP;

  // B staging roles (per wave-instr of global_load_lds): lane -> expert/chunk
  const int be_rel = lane >> 2;          // 0..15 expert within 16-group
  const int bchunk = lane & 3;           // dest chunk (16B)

  auto load_x = [&](int kt) {
    xP = x4[(size_t)(row0 + a_row) * D4 + kt * 8 + a_c];
  };
  auto stage_B = [&](int kt, int p) {
    const int k0 = kt * 32;
#pragma unroll
    for (int j = 0; j < 2; ++j) {
      const int e  = wv * 32 + j * 16 + be_rel;
      const int cs = bchunk ^ swz4(e);                 // swizzled source chunk
      const size_t go = (size_t)e * D + k0 + cs * 8;
      gload_lds16(whi + go, &sm.u.st.Bh[p][(wv * 32 + j * 16) * 32]);
      gload_lds16(wlo + go, &sm.u.st.Bl[p][(wv * 32 + j * 16) * 32]);
    }
  };
  auto store_A = [&](int p) {
    float av[4] = {xP.x, xP.y, xP.z, xP.w};
    ushort_t h[4], l[4];
#pragma unroll
    for (int i = 0; i < 4; ++i) {
      h[i] = f2bf(av[i]);
      l[i] = f2bf(av[i] - bf2f(h[i]));
    }
    const int c  = a_c >> 1, hh = a_c & 1;
    const int sl = (c ^ swz4(a_row)) * 8 + hh * 4;
    *(uint2*)&sm.u.st.Ah[p][a_row * 32 + sl] = *(uint2*)h;
    *(uint2*)&sm.u.st.Al[p][a_row * 32 + sl] = *(uint2*)l;
  };

  // MFMA fragment addressing (32x32x16 bf16, verified in R3):
  // A m=lane&31, k=(lane>>5)*8+j; C col=lane&31, row=(reg&3)+8*(reg>>2)+4*(lane>>5)
  const int m  = lane & 31;
  const int hf = lane >> 5;
  const int sA    = swz4(m);               // == swz4 of A row and of both B rows
  const int aRow  = (rb * 32 + m) * 32;
  const int b0Row = (eg * 64 + m) * 32;
  const int b1Row = (eg * 64 + 32 + m) * 32;

  // ---- pipelined K loop: 1 barrier/tile, double-buffered LDS ----
  load_x(0);
  stage_B(0, 0);
  store_A(0);
  load_x(1);
  __syncthreads();

  for (int kt = 0; kt < NTILE; ++kt) {
    const int p = kt & 1;
    if (kt + 1 < NTILE) {
      stage_B(kt + 1, p ^ 1);      // async, lands before end-of-tile barrier
      store_A(p ^ 1);              // consumes xP(kt+1)
      if (kt + 2 < NTILE) load_x(kt + 2);
    }
#pragma unroll
    for (int ks = 0; ks < 2; ++ks) {
      const int sl = ((2 * ks + hf) ^ sA) * 8;
      short8 ahi = *(const short8*)&sm.u.st.Ah[p][aRow + sl];
      short8 alo = *(const short8*)&sm.u.st.Al[p][aRow + sl];
      short8 b0h = *(const short8*)&sm.u.st.Bh[p][b0Row + sl];
      short8 b0l = *(const short8*)&sm.u.st.Bl[p][b0Row + sl];
      short8 b1h = *(const short8*)&sm.u.st.Bh[p][b1Row + sl];
      short8 b1l = *(const short8*)&sm.u.st.Bl[p][b1Row + sl];
      acc0 = __builtin_amdgcn_mfma_f32_32x32x16_bf16(ahi, b0h, acc0, 0, 0, 0);
      acc0 = __builtin_amdgcn_mfma_f32_32x32x16_bf16(ahi, b0l, acc0, 0, 0, 0);
      acc0 = __builtin_amdgcn_mfma_f32_32x32x16_bf16(alo, b0h, acc0, 0, 0, 0);
      acc1 = __builtin_amdgcn_mfma_f32_32x32x16_bf16(ahi, b1h, acc1, 0, 0, 0);
      acc1 = __builtin_amdgcn_mfma_f32_32x32x16_bf16(ahi, b1l, acc1, 0, 0, 0);
      acc1 = __builtin_amdgcn_mfma_f32_32x32x16_bf16(alo, b1h, acc1, 0, 0, 0);
    }
    __syncthreads();
  }

  // ---- per-wave top-8 over this wave's 64 experts, per row ----
  const int e0id = eg * 64 + m;
  const int e1id = eg * 64 + 32 + m;
  const float bia0 = sm.bias[e0id];
  const float bia1 = sm.bias[e1id];

#pragma unroll
  for (int reg = 0; reg < 16; ++reg) {
    const int row_local = rb * 32 + (reg & 3) + 8 * (reg >> 2) + 4 * hf;
    float s0 = acc0[reg], s1 = acc1[reg];
    float v0 = sqrtf(fmaxf(s0, 0.f) + log1pf(expf(-fabsf(s0)))) + bia0;
    float v1 = sqrtf(fmaxf(s1, 0.f) + log1pf(expf(-fabsf(s1)))) + bia1;
    float tv[8]; int ti[8];
#pragma unroll
    for (int s = 0; s < 8; ++s) {
      float bv; int bi;
      if (v0 >= v1) { bv = v0; bi = e0id; } else { bv = v1; bi = e1id; }
#pragma unroll
      for (int off = 1; off < 32; off <<= 1) {
        float ov = __shfl_xor(bv, off, 64);
        int   oi = __shfl_xor(bi, off, 64);
        if (ov > bv || (ov == bv && oi < bi)) { bv = ov; bi = oi; }
      }
      tv[s] = bv; ti[s] = bi;
      if (bi == e0id) v0 = -INFINITY;
      else if (bi == e1id) v1 = -INFINITY;
    }
    if (m == 0) {
#pragma unroll
      for (int s = 0; s < 8; ++s) {
        sm.u.mg.val[row_local * 33 + eg * 8 + s] = tv[s];
        sm.u.mg.id [row_local * 33 + eg * 8 + s] = ti[s];
      }
    }
  }
  __syncthreads();

  // ---- merge 4x8 -> global top-8 per row; flag ambiguous rows ----
  {
    const int r = t >> 3, g = t & 7;
    float mv[4]; int mi[4];
#pragma unroll
    for (int q = 0; q < 4; ++q) {
      mv[q] = sm.u.mg.val[r * 33 + q * 8 + g];
      mi[q] = sm.u.mg.id [r * 33 + q * 8 + g];
    }
    float tv[8]; int ti[8];
#pragma unroll
    for (int s = 0; s < 8; ++s) {
      float bv = mv[0]; int bi = mi[0];
#pragma unroll
      for (int q = 1; q < 4; ++q)
        if (mv[q] > bv || (mv[q] == bv && mi[q] < bi)) { bv = mv[q]; bi = mi[q]; }
#pragma unroll
      for (int off = 1; off < 8; off <<= 1) {
        float ov = __shfl_xor(bv, off, 64);
        int   oi = __shfl_xor(bi, off, 64);
        if (ov > bv || (ov == bv && oi < bi)) { bv = ov; bi = oi; }
      }
      tv[s] = bv; ti[s] = bi;
#pragma unroll
      for (int q = 0; q < 4; ++q)
        if (mi[q] == bi) mv[q] = -INFINITY;
    }
    if (g == 0) {
      bool flag = false;
#pragma unroll
      for (int i = 0; i < 7; ++i) flag |= (tv[i] - tv[i + 1] < TAU);
      const int grow = row0 + r;
      if (!flag) {
        float og[6], ssum = 0.f;
#pragma unroll
        for (int i = 0; i < 6; ++i) { og[i] = tv[i] - sm.bias[ti[i]]; ssum += og[i]; }
        const float sc = 1.5f / ssum;
#pragma unroll
        for (int i = 0; i < 6; ++i) {
          outw[(size_t)grow * TK + i] = og[i] * sc;
          outi[(size_t)grow * TK + i] = (float)ti[i];
        }
      } else {
        int slot = atomicAdd(&sm.nflag, 1);
        sm.flagrow[slot] = grow;
#pragma unroll
        for (int i = 0; i < 8; ++i) sm.flagid[slot][i] = ti[i];
      }
    }
  }
  __syncthreads();

  // ---- exact fp64 rescue for flagged rows (expected <1/block) ----
  const int nf = sm.nflag;
  for (int f = 0; f < nf; ++f) {
    const int grow = sm.flagrow[f];
    const int e    = sm.flagid[f][wv];
    double accd = 0.0;
    const float4* xr = x4 + (size_t)grow * D4 + lane * 16;
    const float4* wr = w4 + (size_t)e    * D4 + lane * 16;
#pragma unroll
    for (int i = 0; i < 16; ++i) {
      float4 xv = xr[i], wl = wr[i];
      accd = fma((double)xv.x, (double)wl.x, accd);
      accd = fma((double)xv.y, (double)wl.y, accd);
      accd = fma((double)xv.z, (double)wl.z, accd);
      accd = fma((double)xv.w, (double)wl.w, accd);
    }
#pragma unroll
    for (int off = 1; off < 64; off <<= 1)
      accd += __shfl_xor(accd, off, 64);
    if (lane == 0) {
      double sp = fmax(accd, 0.0) + log1p(exp(-fabs(accd)));
      sm.exact[wv] = sqrt(sp);   // orig (unbiased) score
    }
    __syncthreads();
    if (t == 0) {
      double ov[8]; int oid[8], ordr[8];
      for (int i = 0; i < 8; ++i) { ov[i] = sm.exact[i]; oid[i] = sm.flagid[f][i]; ordr[i] = i; }
      for (int i = 0; i < 6; ++i) {
        int b = i;
        for (int j = i + 1; j < 8; ++j) {
          double bj = ov[ordr[j]] + (double)sm.bias[oid[ordr[j]]];
          double bb = ov[ordr[b]] + (double)sm.bias[oid[ordr[b]]];
          if (bj > bb || (bj == bb && oid[ordr[j]] < oid[ordr[b]])) b = j;
        }
        int tmp = ordr[i]; ordr[i] = ordr[b]; ordr[b] = tmp;
      }
      double ssum = 0.0;
      for (int i = 0; i < 6; ++i) ssum += ov[ordr[i]];
      double sc = 1.5 / ssum;
      for (int i = 0; i < 6; ++i) {
        outw[(size_t)grow * TK + i] = (float)(ov[ordr[i]] * sc);
        outi[(size_t)grow * TK + i] = (float)oid[ordr[i]];
      }
    }
    __syncthreads();
  }
}

extern "C" void kernel_launch(void* const* d_in, const int* in_sizes, int n_in,
                              void* d_out, int out_size, void* d_ws, size_t ws_size,
                              hipStream_t stream) {
  const float* x = (const float*)d_in[0];
  const float* w = (const float*)d_in[1];
  const float* b = (const float*)d_in[2];
  float* out  = (float*)d_out;
  const int N = in_sizes[0] / D;          // 16384

  ushort_t* whi = (ushort_t*)d_ws;                      // E*D bf16 = 2 MB
  ushort_t* wlo = whi + (size_t)E * D;                  // +2 MB

  float* outw = out;                      // [N,6] weights
  float* outi = out + (size_t)N * TK;     // [N,6] indices (as float)

  hipLaunchKernelGGL(conv_w, dim3(E * D / 4 / 256), dim3(256), 0, stream,
                     w, whi, wlo);
  hipLaunchKernelGGL(gate_kernel, dim3(N / BM), dim3(NT), 0, stream,
                     x, w, b, whi, wlo, outw, outi);
}